// Round 2
// baseline (1013.798 us; speedup 1.0000x reference)
//
#include <hip/hip_runtime.h>
#include <stdint.h>
#include <math.h>

// EncoderSRNN: T=127 steps, BSZ=32 items, HDIM=256, SDIM=128, SSZ=128.
// One WG (1024 threads = 16 waves) per item. v3: 2 raw barriers/step:
//  - inst/softmax moved to Phase A via bilinear collapse: inst = window(E2I)
//    + tops.P2 + const, with E2I = E2H@Wh2i^T, P2 = Wh2i@Ws2h precomputed
//    (f32) in prep. pp/pq ready at barrier 1.
//  - Phase B and stack phase merged: stack rows 1-127 need only pp/pq; row 0
//    computed by the B GEMV lanes via shfl_xor(8) swap of pv/uv (h2s lanes
//    interleaved with s2u lanes at lane-bit 3). s_pk double-buffered.
//  - all in-loop barriers are raw: s_waitcnt lgkmcnt(0); s_barrier (no vmcnt
//    drain -> global stores don't stall barriers).

#define T_STEPS 127

// flat f32 output offsets (outputs, hid, stack, acts, top_elems)
#define OUT_OFF   0
#define HID_OFF   1040384
#define STACK_OFF 1048576
#define ACTS_OFF  1572864
#define TE_OFF    1580992

// ws layout:
//  uint4 [0,16384):      W1 = s2h (tid<512) / h2h (tid>=512), per-thread 16 uint4
//  uint4 [16384,20480):  W3 = h2s, K-split-8 layout, per-thread 8 uint4
//  uint4 [20480,24576):  W2 = s2u, K-split-8 layout, per-thread 8 uint4
//  uint  [131072,393216): E2H f16-pairs per item
//  f32   [393216,401408): E2I per item: [b][jj*64+row], 192 used of 256 stride
//  f32   [401408,402176): P2: [jj*256+k]
//  f32   [402176,402179): cvec (includes b_h2i)
#define W3_OFF 16384
#define W2_OFF 20480
#define E2H_OFF_U 131072
#define E2I_F 393216
#define P2_F  401408
#define CVEC_F 402176

typedef _Float16 h2 __attribute__((ext_vector_type(2)));

__device__ __forceinline__ unsigned packh2(float a, float b){
  h2 v; v.x = (_Float16)a; v.y = (_Float16)b;
  return __builtin_bit_cast(unsigned, v);
}
__device__ __forceinline__ float h2loF(unsigned u){ h2 v = __builtin_bit_cast(h2,u); return (float)v.x; }
__device__ __forceinline__ float h2hiF(unsigned u){ h2 v = __builtin_bit_cast(h2,u); return (float)v.y; }

#if __has_builtin(__builtin_amdgcn_fdot2)
__device__ __forceinline__ float fdot2(unsigned a, unsigned b, float c){
  return __builtin_amdgcn_fdot2(__builtin_bit_cast(h2,a), __builtin_bit_cast(h2,b), c, false);
}
#else
__device__ __forceinline__ float fdot2(unsigned a, unsigned b, float c){
  return c + h2loF(a)*h2loF(b) + h2hiF(a)*h2hiF(b);
}
#endif

// raw barrier: LDS-only drain, no vmcnt (global stores don't gate the barrier)
#define BAR() asm volatile("s_waitcnt lgkmcnt(0)\n\ts_barrier" ::: "memory")

// chunked (bank-staggered) layout for packed act vectors
#define CHOFF(u) (12*((u)>>3) + ((u)&7))
// staggered f32 layout for acc arrays (pair index p)
#define STGP(p)  (20*((p)>>3) + 2*((p)&7))

// ---------------- fused prep ----------------
// blocks [0,256): E2H (f32 weights) + E2I rows
// blocks [256,352): pack W1/W3/W2 f16 blobs
// block 352: P2 + cvec
__global__ void prep_all(const int* __restrict__ inputs, const float* __restrict__ embW,
                         const float* __restrict__ We2h,
                         const float* __restrict__ Ws2h, const float* __restrict__ Wh2h,
                         const float* __restrict__ Wh2s, const float* __restrict__ Ws2u,
                         const float* __restrict__ Wh2i,
                         const float* __restrict__ b_e2h, const float* __restrict__ b_s2h,
                         const float* __restrict__ b_h2i,
                         unsigned* __restrict__ wsu){
  int tid = threadIdx.x;
  int bi  = blockIdx.x;
  uint4* out4 = (uint4*)wsu;
  unsigned* e2hpk = wsu + E2H_OFF_U;
  float* wsf = (float*)wsu;
  if (bi >= 256 && bi < 352){
    int gid = (bi-256)*256 + tid;              // [0, 24576)
    const float* src;
    if (gid < 16384){                          // W1
      int i = gid >> 10, t_ = gid & 1023;
      const float* S = (t_ < 512) ? Ws2h : Wh2h;
      int r = t_ & 511, jp = r >> 2, ks = r & 3;
      int j  = 2*jp + (i >> 3);
      int k0 = ks*64 + (i & 7)*8;
      src = S + j*256 + k0;
    } else {                                   // W3 / W2, K-split-8 layout
      int l = gid - 16384;
      int region = l >> 12, li = l & 4095;     // 0: h2s, 1: s2u
      int i = li >> 9, rB = li & 511;
      int jp = rB >> 3, ks = rB & 7;
      int j  = 2*jp + (i >> 2);
      int k0 = ks*32 + (i & 3)*8;
      src = (region ? Ws2u : Wh2s) + j*256 + k0;
    }
    uint4 r4;
    r4.x = packh2(src[0], src[1]); r4.y = packh2(src[2], src[3]);
    r4.z = packh2(src[4], src[5]); r4.w = packh2(src[6], src[7]);
    out4[gid] = r4;
    return;
  }
  if (bi == 352){
    // P2[jj][k] = sum_m Wh2i[jj,m] * Ws2h[m,k];  cvec[jj] = (b_e2h+b_s2h).Wh2i_jj + b_h2i[jj]
    int k = tid;
    float s0=0.f, s1=0.f, s2=0.f;
    for (int m=0;m<256;m++){
      float wmk = Ws2h[m*256+k];
      s0 += Wh2i[m]*wmk; s1 += Wh2i[256+m]*wmk; s2 += Wh2i[512+m]*wmk;
    }
    wsf[P2_F +       k] = s0;
    wsf[P2_F + 256 + k] = s1;
    wsf[P2_F + 512 + k] = s2;
    if (tid < 3){
      float c = b_h2i[tid];
      for (int m=0;m<256;m++) c += (b_e2h[m]+b_s2h[m])*Wh2i[tid*256+m];
      wsf[CVEC_F + tid] = c;
    }
    return;
  }
  // ---- E2H + E2I ----
  __shared__ float emb[8][256];
  __shared__ float red[3][4][8];
  int r2 = bi >> 3, bg = bi & 7;
  for (int q=0;q<8;q++){
    int rr = q >> 2, bb = q & 3;
    int tok = inputs[(2*r2+rr)*32 + bg*4+bb];
    emb[q][tid] = embW[tok*256 + tid];
  }
  __syncthreads();
  float acc[8] = {0.f,0.f,0.f,0.f,0.f,0.f,0.f,0.f};
  for (int i8=0;i8<32;i8++){
    float4 f0 = *(const float4*)&We2h[tid*256 + i8*8];
    float4 f1 = *(const float4*)&We2h[tid*256 + i8*8 + 4];
    float wv[8] = {f0.x,f0.y,f0.z,f0.w,f1.x,f1.y,f1.z,f1.w};
    #pragma unroll
    for (int c=0;c<4;c++){
      float lo = wv[2*c], hi = wv[2*c+1];
      int k = i8*8 + c*2;
      #pragma unroll
      for (int q=0;q<8;q++)
        acc[q] += emb[q][k]*lo + emb[q][k+1]*hi;
    }
  }
  int base = (bg*4)*8192 + r2*256 + tid;
  #pragma unroll
  for (int bb=0;bb<4;bb++)
    e2hpk[base + bb*8192] = packh2(acc[bb], acc[4+bb]);
  // E2I: reduce acc over cols against Wh2i rows
  int wv_ = tid>>6, ln = tid&63;
  for (int jj=0;jj<3;jj++){
    float w = Wh2i[jj*256 + tid];
    float v[8];
    #pragma unroll
    for (int q=0;q<8;q++) v[q] = acc[q]*w;
    #pragma unroll
    for (int o=1;o<=32;o<<=1){
      #pragma unroll
      for (int q=0;q<8;q++) v[q] += __shfl_xor(v[q],o);
    }
    if (ln==0){
      #pragma unroll
      for (int q=0;q<8;q++) red[jj][wv_][q] = v[q];
    }
  }
  __syncthreads();
  if (tid < 24){
    int jj = tid>>3, q = tid&7;
    float s = red[jj][0][q]+red[jj][1][q]+red[jj][2][q]+red[jj][3][q];
    int rr = q>>2, bb = q&3;
    wsf[E2I_F + (4*bg+bb)*256 + jj*64 + (2*r2+rr)] = s;
  }
}

// ---------------- main sequential kernel ----------------
__global__ __attribute__((amdgpu_flat_work_group_size(1024,1024), amdgpu_waves_per_eu(4,4)))
void srnn_main(const uint4* __restrict__ ws4, const unsigned* __restrict__ wsu,
               const float* __restrict__ b_e2h, const float* __restrict__ b_s2h,
               const float* __restrict__ b_h2h,
               const float* __restrict__ b_h2s, const float* __restrict__ b_s2u,
               const float* __restrict__ empty_el, float* __restrict__ out)
{
  __shared__ __align__(16) float    stk_s[128*128];     // stack rows (row0 unused), 64 KB
  __shared__ __align__(16) unsigned e2h4[16*520];       // pair-interleaved e2h
  __shared__ __align__(16) float    halo_top[2][16*128];
  __shared__ __align__(16) float    halo_bot[2][16*128];
  __shared__ __align__(16) float    row0_lds[2][128];   // stack row 0, dbuf
  __shared__ __align__(16) float    accih_st[320], acchp_st[320];
  __shared__ __align__(16) unsigned s_pk[2][192];       // tops f16, chunked, dbuf
  __shared__ __align__(16) unsigned hid_pk[192];
  __shared__ __align__(16) float    e2i_s[192];         // [jj*64+row]
  __shared__ __align__(16) float    p2_s[768];          // [jj*256+k]
  __shared__ float    wbuf[2][192];
  __shared__ unsigned pkwc[32];
  __shared__ float    pp_s, pq_s;

  const int tid = threadIdx.x;
  const int b   = blockIdx.x;
  const int aside = tid >> 9;           // A: 0=ih(s2h+window), 1=hp(h2h)
  const int ar  = tid & 511;
  const int ajp = ar >> 2;              // A output pair 0..127
  const int aks = ar & 3;               // A K-split 4
  const int jpB = tid >> 4;             // B output pair 0..63
  const int which = (tid >> 3) & 1;     // B: 0=s2u(uv), 1=h2s(pv)
  const int ksB = tid & 7;              // B K-split 8
  const int g   = tid >> 6;             // stack: wave id = row-group
  const int cp  = tid & 63;             // stack: column pair

  // ---- preload weights into registers ----
  uint4 w1r[16], wBr[8];
  #pragma unroll
  for (int i=0;i<16;i++) w1r[i] = ws4[i*1024 + tid];
  {
    int wbase = which ? W3_OFF : W2_OFF;
    int rIdx  = jpB*8 + ksB;
    #pragma unroll
    for (int i=0;i<8;i++) wBr[i] = ws4[wbase + i*512 + rIdx];
  }

  float bA0=0.f, bA1=0.f;
  if (aks==0){
    int j0 = 2*ajp;
    if (aside==0){ bA0 = b_e2h[j0]+b_s2h[j0]; bA1 = b_e2h[j0+1]+b_s2h[j0+1]; }
    else         { bA0 = b_h2h[j0];           bA1 = b_h2h[j0+1]; }
  }
  const float* bbB = which ? b_h2s : b_s2u;
  const float bB0 = bbB[2*jpB], bB1 = bbB[2*jpB+1];
  const float* wsf = (const float*)wsu;
  float c0r=0.f, c1r=0.f, c2r=0.f;
  if (tid >= 960){ c0r = wsf[CVEC_F]; c1r = wsf[CVEC_F+1]; c2r = wsf[CVEC_F+2]; }

  // ---- init LDS state ----
  const unsigned* e2hg = wsu + E2H_OFF_U + b*8192;
  #pragma unroll
  for (int q=0;q<8;q++){
    int idx = q*1024 + tid;
    int r2 = idx >> 8, j = idx & 255;
    e2h4[(r2>>1)*520 + 2*j + (r2&1)] = e2hg[idx];
  }
  const float2 emt2 = *(const float2*)&empty_el[2*cp];
  #pragma unroll
  for (int j=0;j<8;j++)
    *(float2*)&stk_s[(8*g+j)*128 + 2*cp] = emt2;
  *(float2*)&halo_top[0][g*128 + 2*cp] = emt2;
  *(float2*)&halo_bot[0][g*128 + 2*cp] = emt2;
  if (tid < 128) row0_lds[0][tid] = empty_el[tid];
  if (tid < 192) e2i_s[tid] = wsf[E2I_F + b*256 + tid];
  if (tid < 768) p2_s[tid] = wsf[P2_F + tid];
  if (tid < 128){
    hid_pk[CHOFF(tid)] = 0u;
    int cu = tid & 63;
    s_pk[0][CHOFF(tid)] = packh2(empty_el[2*cu], empty_el[2*cu+1]);
  }
  if (tid < 192){ wbuf[0][tid] = (tid==64)?1.f:0.f; wbuf[1][tid]=0.f; }
  if (tid < 32)  pkwc[tid] = (tid==0)? packh2(1.f,0.f) : 0u;
  __syncthreads();

  int cur = 0;
  for (int t=0;t<T_STEPS;++t){
    // ============ Phase A: ih (s2h+window), hp (h2h), inst+softmax ============
    {
      const unsigned* act  = aside ? hid_pk : s_pk[cur];
      const unsigned* actB = act + 48*aks;
      float x0 = 0.f, x1 = 0.f;
      if (aside==0){
        #pragma unroll
        for (int qq=0;qq<4;qq++){
          int r2g = 4*aks + qq;
          unsigned cwE = pkwc[8*aks + 2*qq];
          unsigned cwO = pkwc[8*aks + 2*qq + 1];
          uint4 u = *(const uint4*)&e2h4[r2g*520 + 4*ajp];
          x0 = fdot2(cwE, u.x, x0); x0 = fdot2(cwO, u.y, x0);
          x1 = fdot2(cwE, u.z, x1); x1 = fdot2(cwO, u.w, x1);
        }
      }
      #pragma unroll
      for (int i=0;i<8;i++){
        uint4 A  = *(const uint4*)(actB + 12*(i>>1) + 4*(i&1));
        uint4 Wa = w1r[i], Wb = w1r[8+i];
        x0 = fdot2(A.x,Wa.x,x0); x0 = fdot2(A.y,Wa.y,x0);
        x0 = fdot2(A.z,Wa.z,x0); x0 = fdot2(A.w,Wa.w,x0);
        x1 = fdot2(A.x,Wb.x,x1); x1 = fdot2(A.y,Wb.y,x1);
        x1 = fdot2(A.z,Wb.z,x1); x1 = fdot2(A.w,Wb.w,x1);
      }
      x0 += __shfl_xor(x0,1); x0 += __shfl_xor(x0,2);
      x1 += __shfl_xor(x1,1); x1 += __shfl_xor(x1,2);
      if (aks==0){
        float* dst = aside ? acchp_st : accih_st;
        *(float2*)&dst[STGP(ajp)] = make_float2(x0 + bA0, x1 + bA1);
      }
    }
    // ---- inst + softmax on wave 15 (independent of accih) ----
    if (tid >= 960){
      int l = tid - 960;
      float p0, p1, p2v;
      if (l < 32){
        unsigned cw = pkwc[l];
        float cf0 = h2loF(cw), cf1 = h2hiF(cw);
        float2 a0 = *(const float2*)&e2i_s[      2*l];
        float2 a1 = *(const float2*)&e2i_s[ 64 + 2*l];
        float2 a2 = *(const float2*)&e2i_s[128 + 2*l];
        p0  = cf0*a0.x + cf1*a0.y;
        p1  = cf0*a1.x + cf1*a1.y;
        p2v = cf0*a2.x + cf1*a2.y;
      } else {
        int c = l - 32;
        p0 = p1 = p2v = 0.f;
        #pragma unroll
        for (int m=0;m<4;m++){
          int k2 = c + 32*m;
          unsigned tp = s_pk[cur][CHOFF(k2)];
          float t0 = h2loF(tp), t1 = h2hiF(tp);
          float2 q0 = *(const float2*)&p2_s[      2*k2];
          float2 q1 = *(const float2*)&p2_s[256 + 2*k2];
          float2 q2 = *(const float2*)&p2_s[512 + 2*k2];
          p0  += t0*q0.x + t1*q0.y;
          p1  += t0*q1.x + t1*q1.y;
          p2v += t0*q2.x + t1*q2.y;
        }
      }
      #pragma unroll
      for (int o=1;o<=32;o<<=1){
        p0 += __shfl_xor(p0,o); p1 += __shfl_xor(p1,o); p2v += __shfl_xor(p2v,o);
      }
      if (l == 0){
        float i0 = c0r+p0, i1 = c1r+p1, gi = c2r+p2v;
        float mx = fmaxf(i0,i1);
        float e0 = expf(i0-mx), e1 = expf(i1-mx);
        float inv = 1.f/(e0+e1);
        float act0 = e0*inv, act1 = e1*inv;
        float gamma = 1.f + log1pf(expf(gi));
        float A0 = powf(act0,gamma), A1 = powf(act1,gamma);
        float sden = A0+A1+1e-16f;
        float ppv = A0/sden, pqv = A1/sden;
        pp_s = ppv; pq_s = pqv;
        *(float2*)&out[ACTS_OFF + t*64 + b*2] = make_float2(ppv,pqv);
      }
    }
    BAR();                                             // barrier 1

    const float pp = pp_s, pq = pq_s;

    // ---- hid finalize (tid 64..191) ----
    if (tid >= 64 && tid < 192){
      int hl = tid - 64;
      int w_ = STGP(hl);
      float2 ih2 = *(const float2*)&accih_st[w_];
      float2 hp2 = *(const float2*)&acchp_st[w_];
      float hn0 = fmaxf(ih2.x+hp2.x, 0.f);
      float hn1 = fmaxf(ih2.y+hp2.y, 0.f);
      hid_pk[CHOFF(hl)] = packh2(hn0,hn1);
      *(float2*)&out[OUT_OFF + t*8192 + b*256 + 2*hl] = make_float2(hn0,hn1);
      if (t==T_STEPS-1) *(float2*)&out[HID_OFF + b*256 + 2*hl] = make_float2(hn0,hn1);
    }

    // ============ Phase B GEMV: h2s (inline hid) / s2u + row0 ============
    {
      float y0=0.f, y1=0.f;
      #pragma unroll
      for (int i=0;i<4;i++){
        unsigned u0,u1,u2,u3;
        if (which){
          const int off = 40*ksB + ((i>=2)?20:0) + 8*(i&1);
          float4 a0 = *(const float4*)(accih_st + off);
          float4 a1 = *(const float4*)(accih_st + off + 4);
          float4 c0 = *(const float4*)(acchp_st + off);
          float4 c1 = *(const float4*)(acchp_st + off + 4);
          u0 = packh2(fmaxf(a0.x+c0.x,0.f), fmaxf(a0.y+c0.y,0.f));
          u1 = packh2(fmaxf(a0.z+c0.z,0.f), fmaxf(a0.w+c0.w,0.f));
          u2 = packh2(fmaxf(a1.x+c1.x,0.f), fmaxf(a1.y+c1.y,0.f));
          u3 = packh2(fmaxf(a1.z+c1.z,0.f), fmaxf(a1.w+c1.w,0.f));
        } else {
          uint4 S = *(const uint4*)&s_pk[cur][12*(2*ksB + (i>>1)) + 4*(i&1)];
          u0 = S.x; u1 = S.y; u2 = S.z; u3 = S.w;
        }
        uint4 Wa = wBr[i], Wb = wBr[4+i];
        y0=fdot2(u0,Wa.x,y0); y0=fdot2(u1,Wa.y,y0); y0=fdot2(u2,Wa.z,y0); y0=fdot2(u3,Wa.w,y0);
        y1=fdot2(u0,Wb.x,y1); y1=fdot2(u1,Wb.y,y1); y1=fdot2(u2,Wb.z,y1); y1=fdot2(u3,Wb.w,y1);
      }
      y0 += __shfl_xor(y0,1); y0 += __shfl_xor(y0,2); y0 += __shfl_xor(y0,4);
      y1 += __shfl_xor(y1,1); y1 += __shfl_xor(y1,2); y1 += __shfl_xor(y1,4);
      float v0 = fmaxf(y0+bB0, 0.f), v1 = fmaxf(y1+bB1, 0.f);
      float o0 = __shfl_xor(v0, 8),  o1 = __shfl_xor(v1, 8);
      if (!which && ksB==0){
        // this lane: uv = (v0,v1); partner (h2s): pv = (o0,o1)
        float n0 = pp*o0 + pq*v0;
        float n1 = pp*o1 + pq*v1;
        *(float2*)&row0_lds[cur^1][2*jpB] = make_float2(n0,n1);
        s_pk[cur^1][CHOFF(jpB)] = packh2(n0,n1);
        *(float2*)&out[TE_OFF + t*4096 + b*128 + 2*jpB] = make_float2(n0,n1);
      }
    }

    // ---- coefficient recurrence ----
    if (tid < 128){
      int k = 64+tid;
      wbuf[cur^1][k] = pp*wbuf[cur][k] + pq*wbuf[cur][k-1];
    } else if (tid < 160){
      int r2 = tid-128;
      int k1 = 65 + t - 2*r2;
      float wa = wbuf[cur][k1], wb2 = wbuf[cur][k1-1], wc2 = wbuf[cur][k1-2];
      pkwc[r2] = packh2(pp*wa+pq*wb2, pp*wb2+pq*wc2);
    }

    // ============ Stack rows (own rows in stk_s, halos dbuf) ============
    {
      float2 w[10];
      #pragma unroll
      for (int k=1;k<=8;k++)
        w[k] = *(const float2*)&stk_s[(8*g + k - 1)*128 + 2*cp];
      if (g==0) w[1] = *(const float2*)&row0_lds[cur][2*cp];
      w[0] = (g>0)  ? *(const float2*)&halo_bot[cur][(g-1)*128 + 2*cp]
                    : make_float2(0.f,0.f);
      w[9] = (g<15) ? *(const float2*)&halo_top[cur][(g+1)*128 + 2*cp]
                    : emt2;
      #pragma unroll
      for (int j=0;j<8;j++){
        if (j==0 && g==0) continue;            // row 0 handled by B lanes
        float2 nv;
        nv.x = pp*w[j].x + pq*w[j+2].x;
        nv.y = pp*w[j].y + pq*w[j+2].y;
        *(float2*)&stk_s[(8*g+j)*128 + 2*cp] = nv;
        if (j==0) *(float2*)&halo_top[cur^1][g*128 + 2*cp] = nv;
        if (j==7) *(float2*)&halo_bot[cur^1][g*128 + 2*cp] = nv;
        if (j==1 && g==0) s_pk[cur^1][CHOFF(64+cp)] = packh2(nv.x, nv.y);
      }
    }
    BAR();                                             // barrier 2
    cur ^= 1;
  }

  // ---- final stack output ----
  #pragma unroll
  for (int j=0;j<8;j++){
    int r = 8*g + j;
    float2 v;
    if (g==0 && j==0) v = *(const float2*)&row0_lds[cur][2*cp];
    else              v = *(const float2*)&stk_s[r*128 + 2*cp];
    *(float2*)&out[STACK_OFF + b*16384 + r*128 + 2*cp] = v;
  }
}

extern "C" void kernel_launch(void* const* d_in, const int* in_sizes, int n_in,
                              void* d_out, int out_size, void* d_ws, size_t ws_size,
                              hipStream_t stream){
  const int*   inputs = (const int*)d_in[0];
  const float* embW   = (const float*)d_in[1];
  const float* We2h   = (const float*)d_in[2];
  const float* b_e2h  = (const float*)d_in[3];
  const float* Ws2h   = (const float*)d_in[4];
  const float* b_s2h  = (const float*)d_in[5];
  const float* Wh2h   = (const float*)d_in[6];
  const float* b_h2h  = (const float*)d_in[7];
  const float* Wh2i   = (const float*)d_in[8];
  const float* b_h2i  = (const float*)d_in[9];
  const float* Wh2s   = (const float*)d_in[10];
  const float* b_h2s  = (const float*)d_in[11];
  const float* Ws2u   = (const float*)d_in[12];
  const float* b_s2u  = (const float*)d_in[13];
  const float* empty  = (const float*)d_in[14];
  unsigned* wsu = (unsigned*)d_ws;

  prep_all<<<dim3(353), dim3(256), 0, stream>>>(inputs, embW, We2h, Ws2h, Wh2h,
                                                Wh2s, Ws2u, Wh2i, b_e2h, b_s2h,
                                                b_h2i, wsu);
  srnn_main<<<dim3(32), dim3(1024), 0, stream>>>((const uint4*)wsu, (const unsigned*)wsu,
                                                 b_e2h, b_s2h, b_h2h,
                                                 b_h2s, b_s2u, empty, (float*)d_out);
}

// Round 3
// 897.188 us; speedup vs baseline: 1.1300x; 1.1300x over previous
//
#include <hip/hip_runtime.h>
#include <stdint.h>
#include <math.h>

// EncoderSRNN: T=127 steps, BSZ=32 items, HDIM=256, SDIM=128, SSZ=128.
// One WG (1024 threads = 16 waves) per item, 1 block/CU. All GEMV weights
// register-resident as f16 (96 VGPR/thread), v_dot2_f32_f16. Stack f32 in LDS,
// column-parallel conflict-free update. buf recurrence collapsed to a 128-coeff
// scalar window over precomputed E2H (emb@We2h^T) since emb_W[PAD]==0.
// v5 = round-0 structure (best known) with raw barriers: in-loop barriers are
// `s_waitcnt lgkmcnt(0); s_barrier` so global stores (hid/acts/TE) don't gate
// the barrier with a vmcnt(0) drain. Single-variable change vs round-0.

#define T_STEPS 127

// flat f32 output offsets (outputs, hid, stack, acts, top_elems)
#define OUT_OFF   0
#define HID_OFF   1040384
#define STACK_OFF 1048576
#define ACTS_OFF  1572864
#define TE_OFF    1580992

// ws layout (uint4 granularity for weight blobs):
//  uint4 [0,16384):      W1 = s2h (tid<512) / h2h (tid>=512), per-thread 16 uint4
//  uint4 [16384,20480):  W3 = h2s, per-thread 4 uint4
//  uint4 [20480,24576):  W2 = s2u, per-thread 4 uint4
//  uint4 [24576,32768):  W0 = We2h^T packed [k-chunk][j] for prep_e2h
//  uint  [131072,393216): E2H f16-pairs per item: [b][r2*256+j] = (row2r2,row2r2+1)
#define E2H_OFF_U 131072

typedef _Float16 h2 __attribute__((ext_vector_type(2)));

__device__ __forceinline__ unsigned packh2(float a, float b){
  h2 v; v.x = (_Float16)a; v.y = (_Float16)b;
  return __builtin_bit_cast(unsigned, v);
}
__device__ __forceinline__ float h2loF(unsigned u){ h2 v = __builtin_bit_cast(h2,u); return (float)v.x; }
__device__ __forceinline__ float h2hiF(unsigned u){ h2 v = __builtin_bit_cast(h2,u); return (float)v.y; }

#if __has_builtin(__builtin_amdgcn_fdot2)
__device__ __forceinline__ float fdot2(unsigned a, unsigned b, float c){
  return __builtin_amdgcn_fdot2(__builtin_bit_cast(h2,a), __builtin_bit_cast(h2,b), c, false);
}
#else
__device__ __forceinline__ float fdot2(unsigned a, unsigned b, float c){
  return c + h2loF(a)*h2loF(b) + h2hiF(a)*h2hiF(b);
}
#endif

// raw barrier: LDS-only drain, no vmcnt (global stores don't gate the barrier).
// Proven correctness-safe in v3 run (passed). Pre-loop barrier stays standard.
#define BAR() asm volatile("s_waitcnt lgkmcnt(0)\n\ts_barrier" ::: "memory")

// chunked (bank-staggered) layout for packed act vectors: logical uint u ->
// physical 12*(u>>3) + (u&7).  16 chunks x 12 uints = 192 uints.
#define CHOFF(u) (12*((u)>>3) + ((u)&7))

// ---------------- prep: pack all weights to f16 blobs ----------------
__global__ void prep_pack(const float* __restrict__ We2h, const float* __restrict__ Ws2h,
                          const float* __restrict__ Wh2h, const float* __restrict__ Wh2s,
                          const float* __restrict__ Ws2u, uint4* __restrict__ out4){
  int gid = blockIdx.x*256 + threadIdx.x;    // [0, 32768)
  const float* src;
  if (gid < 16384){                          // W1: i in [0,16), t in [0,1024)
    int i = gid >> 10, t_ = gid & 1023;
    const float* S = (t_ < 512) ? Ws2h : Wh2h;
    int r = t_ & 511, jp = r >> 2, ks = r & 3;
    int j = 2*jp + (i >> 3);
    int k0 = ks*64 + (i & 7)*8;
    src = S + j*256 + k0;
  } else if (gid < 20480){                   // W3 (h2s): i in [0,4)
    int l = gid - 16384, i = l >> 10, t_ = l & 1023;
    int jr = t_ >> 4, kb = t_ & 15;
    int j = 2*jr + (i >> 1);
    int k0 = kb*16 + (i & 1)*8;
    src = Wh2s + j*256 + k0;
  } else if (gid < 24576){                   // W2 (s2u)
    int l = gid - 20480, i = l >> 10, t_ = l & 1023;
    int jr = t_ >> 4, kb = t_ & 15;
    int j = 2*jr + (i >> 1);
    int k0 = kb*16 + (i & 1)*8;
    src = Ws2u + j*256 + k0;
  } else {                                   // W0: [k-chunk i8][j]
    int l = gid - 24576;
    int i8 = l >> 8, j = l & 255;
    src = We2h + j*256 + i8*8;
  }
  uint4 r4;
  r4.x = packh2(src[0], src[1]); r4.y = packh2(src[2], src[3]);
  r4.z = packh2(src[4], src[5]); r4.w = packh2(src[6], src[7]);
  out4[gid] = r4;
}

// ---------------- prep: E2H = emb @ We2h^T, f16 row-pairs ----------------
__global__ void prep_e2h(const int* __restrict__ inputs, const float* __restrict__ embW,
                         const uint4* __restrict__ w04, unsigned* __restrict__ e2hpk){
  __shared__ float emb[8][256];
  int tid = threadIdx.x;
  int r2 = blockIdx.x >> 3, bg = blockIdx.x & 7;
  for (int q=0;q<8;q++){
    int rr = q >> 2, bb = q & 3;
    int tok = inputs[(2*r2+rr)*32 + bg*4+bb];
    emb[q][tid] = embW[tok*256 + tid];
  }
  __syncthreads();
  float acc[8] = {0.f,0.f,0.f,0.f,0.f,0.f,0.f,0.f};
  for (int i8=0;i8<32;i8++){
    uint4 u = w04[i8*256 + tid];
    unsigned uu[4] = {u.x,u.y,u.z,u.w};
    #pragma unroll
    for (int c=0;c<4;c++){
      float lo = h2loF(uu[c]), hi = h2hiF(uu[c]);
      int k = i8*8 + c*2;
      #pragma unroll
      for (int q=0;q<8;q++)
        acc[q] += emb[q][k]*lo + emb[q][k+1]*hi;
    }
  }
  int base = (bg*4)*8192 + r2*256 + tid;
  #pragma unroll
  for (int bb=0;bb<4;bb++)
    e2hpk[base + bb*8192] = packh2(acc[bb], acc[4+bb]);  // (row 2r2, row 2r2+1)
}

// ---------------- main sequential kernel ----------------
__global__ __attribute__((amdgpu_flat_work_group_size(1024,1024), amdgpu_waves_per_eu(4,4)))
void srnn_main(const uint4* __restrict__ ws4, const unsigned* __restrict__ wsu,
               const float* __restrict__ b_e2h, const float* __restrict__ b_s2h,
               const float* __restrict__ b_h2h, const float* __restrict__ Wh2i,
               const float* __restrict__ b_h2i, const float* __restrict__ b_h2s,
               const float* __restrict__ b_s2u, const float* __restrict__ empty_el,
               float* __restrict__ out)
{
  __shared__ __align__(16) float    stk_s[128*128];     // stack f32, 64 KB, no pad
  __shared__ __align__(16) unsigned e2h_s[32*258];      // f16 pairs, stride 258
  __shared__ __align__(16) unsigned s_pk[192];          // tops f16, chunk-staggered
  __shared__ __align__(16) unsigned hid_pk[192];        // hid f16, chunk-staggered
  __shared__ __align__(16) float    pv_s[128], uv_s[128];
  __shared__ __align__(16) float    accih[256], acchp[256];
  __shared__ __align__(16) float    emptyf_s[128];
  __shared__ float    wbuf[2][192];
  __shared__ unsigned pkwc[32];
  __shared__ float    partsum[12];
  __shared__ float    pp_s, pq_s;

  const int tid = threadIdx.x;
  const int b   = blockIdx.x;
  const int aside = tid >> 9;           // phase A: 0=ih(s2h), 1=hp(h2h)
  const int ar  = tid & 511;
  const int ajp = ar >> 2;              // output pair 0..127
  const int aks = ar & 3;               // K-split 4 (K=64 each)
  const int jr  = tid >> 4;             // phase B output pair 0..63
  const int ksb = tid & 15;             // phase B K-split 16 (K=16 each)
  const int g   = tid >> 6;             // stack: wave id = row-group (8 rows)
  const int cp  = tid & 63;             // stack: column pair

  // ---- preload weights into registers (96 VGPRs) ----
  uint4 w1r[16], w3r[4], w2r[4];
  #pragma unroll
  for (int i=0;i<16;i++) w1r[i] = ws4[i*1024 + tid];
  #pragma unroll
  for (int i=0;i<4;i++)  w3r[i] = ws4[16384 + i*1024 + tid];
  #pragma unroll
  for (int i=0;i<4;i++)  w2r[i] = ws4[20480 + i*1024 + tid];

  float bA0=0.f, bA1=0.f;
  if (aks==0){
    int j0 = 2*ajp;
    if (aside==0){ bA0 = b_e2h[j0]+b_s2h[j0]; bA1 = b_e2h[j0+1]+b_s2h[j0+1]; }
    else         { bA0 = b_h2h[j0];           bA1 = b_h2h[j0+1]; }
  }
  float bH0=0.f,bH1=0.f,bU0=0.f,bU1=0.f;
  if (ksb==0){ bH0=b_h2s[2*jr]; bH1=b_h2s[2*jr+1]; bU0=b_s2u[2*jr]; bU1=b_s2u[2*jr+1]; }
  float rW0=0.f,rW1=0.f,rW2=0.f;
  if (tid<256){ rW0=Wh2i[tid]; rW1=Wh2i[256+tid]; rW2=Wh2i[512+tid]; }
  const float bi0=b_h2i[0], bi1=b_h2i[1], bi2=b_h2i[2];

  // ---- init LDS state ----
  const unsigned* e2hg = wsu + E2H_OFF_U + b*8192;
  #pragma unroll
  for (int q=0;q<8;q++){
    int idx = q*1024 + tid;
    e2h_s[(idx>>8)*258 + (idx&255)] = e2hg[idx];
  }
  {
    float2 e2 = *(const float2*)&empty_el[2*cp];
    #pragma unroll
    for (int j=0;j<8;j++)
      *(float2*)&stk_s[(8*g+j)*128 + 2*cp] = e2;
  }
  if (tid < 128){
    emptyf_s[tid] = empty_el[tid];
    hid_pk[CHOFF(tid)] = 0u;
    int cu = tid & 63;
    s_pk[CHOFF(tid)] = packh2(empty_el[2*cu], empty_el[2*cu+1]);
  }
  if (tid < 192){ wbuf[0][tid] = (tid==64)?1.f:0.f; wbuf[1][tid]=0.f; }
  if (tid < 32)  pkwc[tid] = (tid==0)? packh2(1.f,0.f) : 0u;
  __syncthreads();

  int cur = 0;
  for (int t=0;t<T_STEPS;++t){
    // ============ Phase A: ihid (s2h + inp-window) & hid-pre (h2h) ============
    {
      const unsigned* act  = aside ? hid_pk : s_pk;
      const unsigned* actB = act + 48*aks;
      float x0 = 0.f, x1 = 0.f;
      if (aside==0){
        #pragma unroll
        for (int q=0;q<8;q++){
          int r2 = aks*8 + q;
          unsigned cw = pkwc[r2];
          uint2 e = *(const uint2*)&e2h_s[r2*258 + 2*ajp];
          x0 = fdot2(cw, e.x, x0);
          x1 = fdot2(cw, e.y, x1);
        }
      }
      #pragma unroll
      for (int i=0;i<8;i++){
        uint4 A  = *(const uint4*)(actB + 12*(i>>1) + 4*(i&1));
        uint4 Wa = w1r[i], Wb = w1r[8+i];
        x0 = fdot2(A.x,Wa.x,x0); x0 = fdot2(A.y,Wa.y,x0);
        x0 = fdot2(A.z,Wa.z,x0); x0 = fdot2(A.w,Wa.w,x0);
        x1 = fdot2(A.x,Wb.x,x1); x1 = fdot2(A.y,Wb.y,x1);
        x1 = fdot2(A.z,Wb.z,x1); x1 = fdot2(A.w,Wb.w,x1);
      }
      x0 += __shfl_xor(x0,1); x0 += __shfl_xor(x0,2);
      x1 += __shfl_xor(x1,1); x1 += __shfl_xor(x1,2);
      if (aks==0){
        float* dst = aside ? acchp : accih;
        *(float2*)&dst[2*ajp] = make_float2(x0 + bA0, x1 + bA1);
      }
    }
    BAR();                                             // B1

    // ---- hid update + inst partials ----
    if (tid < 128){
      float2 ih2 = *(const float2*)&accih[2*tid];
      float2 hp2 = *(const float2*)&acchp[2*tid];
      float hn0 = fmaxf(ih2.x+hp2.x, 0.f);
      float hn1 = fmaxf(ih2.y+hp2.y, 0.f);
      hid_pk[CHOFF(tid)] = packh2(hn0,hn1);
      *(float2*)&out[OUT_OFF + t*8192 + b*256 + 2*tid] = make_float2(hn0,hn1);
      if (t==T_STEPS-1) *(float2*)&out[HID_OFF + b*256 + 2*tid] = make_float2(hn0,hn1);
    }
    if (tid < 256){
      float v = accih[tid];
      float p0=v*rW0, p1=v*rW1, p2=v*rW2;
      #pragma unroll
      for (int o=32;o>=1;o>>=1){ p0+=__shfl_xor(p0,o); p1+=__shfl_xor(p1,o); p2+=__shfl_xor(p2,o); }
      if ((tid&63)==0){ int w=tid>>6; partsum[w*3]=p0; partsum[w*3+1]=p1; partsum[w*3+2]=p2; }
    }
    BAR();                                             // B2

    // ---- softmax/gating on wave 0 ----
    if (tid < 64){
      float i0 = bi0+partsum[0]+partsum[3]+partsum[6]+partsum[9];
      float i1 = bi1+partsum[1]+partsum[4]+partsum[7]+partsum[10];
      float gi = bi2+partsum[2]+partsum[5]+partsum[8]+partsum[11];
      float mx = fmaxf(i0,i1);
      float e0 = expf(i0-mx), e1 = expf(i1-mx);
      float inv = 1.f/(e0+e1);
      float act0 = e0*inv, act1 = e1*inv;
      float gamma = 1.f + log1pf(expf(gi));
      float A0 = powf(act0,gamma), A1 = powf(act1,gamma);
      float sden = A0+A1+1e-16f;
      float ppv = A0/sden, pqv = A1/sden;
      if (tid==0){
        pp_s = ppv; pq_s = pqv;
        *(float2*)&out[ACTS_OFF + t*64 + b*2] = make_float2(ppv,pqv);
      }
    }

    // ============ Phase B: h2s (new hid) & s2u (old tops) ============
    {
      const uint4* hptr = (const uint4*)(hid_pk + 12*ksb);
      const uint4* sptr = (const uint4*)(s_pk   + 12*ksb);
      uint4 H0 = hptr[0], H1 = hptr[1];
      uint4 S0 = sptr[0], S1 = sptr[1];
      float h0=0.f,h1=0.f,u0=0.f,u1=0.f;
      h0=fdot2(H0.x,w3r[0].x,h0); h0=fdot2(H0.y,w3r[0].y,h0); h0=fdot2(H0.z,w3r[0].z,h0); h0=fdot2(H0.w,w3r[0].w,h0);
      h0=fdot2(H1.x,w3r[1].x,h0); h0=fdot2(H1.y,w3r[1].y,h0); h0=fdot2(H1.z,w3r[1].z,h0); h0=fdot2(H1.w,w3r[1].w,h0);
      h1=fdot2(H0.x,w3r[2].x,h1); h1=fdot2(H0.y,w3r[2].y,h1); h1=fdot2(H0.z,w3r[2].z,h1); h1=fdot2(H0.w,w3r[2].w,h1);
      h1=fdot2(H1.x,w3r[3].x,h1); h1=fdot2(H1.y,w3r[3].y,h1); h1=fdot2(H1.z,w3r[3].z,h1); h1=fdot2(H1.w,w3r[3].w,h1);
      u0=fdot2(S0.x,w2r[0].x,u0); u0=fdot2(S0.y,w2r[0].y,u0); u0=fdot2(S0.z,w2r[0].z,u0); u0=fdot2(S0.w,w2r[0].w,u0);
      u0=fdot2(S1.x,w2r[1].x,u0); u0=fdot2(S1.y,w2r[1].y,u0); u0=fdot2(S1.z,w2r[1].z,u0); u0=fdot2(S1.w,w2r[1].w,u0);
      u1=fdot2(S0.x,w2r[2].x,u1); u1=fdot2(S0.y,w2r[2].y,u1); u1=fdot2(S0.z,w2r[2].z,u1); u1=fdot2(S0.w,w2r[2].w,u1);
      u1=fdot2(S1.x,w2r[3].x,u1); u1=fdot2(S1.y,w2r[3].y,u1); u1=fdot2(S1.z,w2r[3].z,u1); u1=fdot2(S1.w,w2r[3].w,u1);
      #pragma unroll
      for (int o=8;o>=1;o>>=1){
        h0+=__shfl_xor(h0,o); h1+=__shfl_xor(h1,o);
        u0+=__shfl_xor(u0,o); u1+=__shfl_xor(u1,o);
      }
      if (ksb==0){
        pv_s[2*jr]   = fmaxf(h0+bH0,0.f);
        pv_s[2*jr+1] = fmaxf(h1+bH1,0.f);
        uv_s[2*jr]   = fmaxf(u0+bU0,0.f);
        uv_s[2*jr+1] = fmaxf(u1+bU1,0.f);
      }
    }
    BAR();                                             // B3
    const float pp = pp_s, pq = pq_s;

    // ============ Stack update: column-parallel, conflict-free ============
    {
      float2 w[10];                                    // rows 8g-1 .. 8g+8
      #pragma unroll
      for (int k=0;k<10;k++){
        int r = 8*g - 1 + k;
        if (r >= 0 && r <= 127)
          w[k] = *(const float2*)&stk_s[r*128 + 2*cp];
      }
      if (g == 15) w[9] = *(const float2*)&emptyf_s[2*cp];
      float2 pv2 = make_float2(0.f,0.f), uv2 = make_float2(0.f,0.f);
      if (g == 0){ pv2 = *(const float2*)&pv_s[2*cp]; uv2 = *(const float2*)&uv_s[2*cp]; }
      float2 nn[8];
      #pragma unroll
      for (int j=0;j<8;j++){
        nn[j].x = pp*w[j].x + pq*w[j+2].x;
        nn[j].y = pp*w[j].y + pq*w[j+2].y;
      }
      if (g == 0){
        nn[0].x = pp*pv2.x + pq*uv2.x;
        nn[0].y = pp*pv2.y + pq*uv2.y;
      }
      // coefficient recurrence for the collapsed buf + next-step packed pairs
      if (tid < 128){
        int k = 64+tid;
        wbuf[cur^1][k] = pp*wbuf[cur][k] + pq*wbuf[cur][k-1];
      } else if (tid < 160){
        int r2 = tid-128;
        int k1 = 65 + t - 2*r2;
        float wa = wbuf[cur][k1], wb2 = wbuf[cur][k1-1], wc2 = wbuf[cur][k1-2];
        pkwc[r2] = packh2(pp*wa+pq*wb2, pp*wb2+pq*wc2);
      }
      BAR();                                           // S_e (all reads done)
      #pragma unroll
      for (int j=0;j<8;j++)
        *(float2*)&stk_s[(8*g+j)*128 + 2*cp] = nn[j];
      if (g == 0){
        *(float2*)&out[TE_OFF + t*4096 + b*128 + 2*cp] = nn[0];
        s_pk[CHOFF(cp)]      = packh2(nn[0].x, nn[0].y);
        s_pk[CHOFF(64+cp)]   = packh2(nn[1].x, nn[1].y);
      }
    }
    BAR();                                             // S_f
    cur ^= 1;
  }

  // ---- final stack output ----
  #pragma unroll
  for (int j=0;j<8;j++){
    int r = 8*g + j;
    *(float2*)&out[STACK_OFF + b*16384 + r*128 + 2*cp] =
      *(const float2*)&stk_s[r*128 + 2*cp];
  }
}

extern "C" void kernel_launch(void* const* d_in, const int* in_sizes, int n_in,
                              void* d_out, int out_size, void* d_ws, size_t ws_size,
                              hipStream_t stream){
  const int*   inputs = (const int*)d_in[0];
  const float* embW   = (const float*)d_in[1];
  const float* We2h   = (const float*)d_in[2];
  const float* b_e2h  = (const float*)d_in[3];
  const float* Ws2h   = (const float*)d_in[4];
  const float* b_s2h  = (const float*)d_in[5];
  const float* Wh2h   = (const float*)d_in[6];
  const float* b_h2h  = (const float*)d_in[7];
  const float* Wh2i   = (const float*)d_in[8];
  const float* b_h2i  = (const float*)d_in[9];
  const float* Wh2s   = (const float*)d_in[10];
  const float* b_h2s  = (const float*)d_in[11];
  const float* Ws2u   = (const float*)d_in[12];
  const float* b_s2u  = (const float*)d_in[13];
  const float* empty  = (const float*)d_in[14];
  unsigned* wsu = (unsigned*)d_ws;

  prep_pack<<<dim3(128), dim3(256), 0, stream>>>(We2h, Ws2h, Wh2h, Wh2s, Ws2u, (uint4*)wsu);
  prep_e2h<<<dim3(256), dim3(256), 0, stream>>>(inputs, embW, ((const uint4*)wsu)+24576, wsu + E2H_OFF_U);
  srnn_main<<<dim3(32), dim3(1024), 0, stream>>>((const uint4*)wsu, (const unsigned*)wsu,
                                                 b_e2h, b_s2h, b_h2h, Wh2i, b_h2i,
                                                 b_h2s, b_s2u, empty, (float*)d_out);
}

// Round 4
// 843.217 us; speedup vs baseline: 1.2023x; 1.0640x over previous
//
#include <hip/hip_runtime.h>
#include <stdint.h>
#include <math.h>

// EncoderSRNN: T=127 steps, BSZ=32 items, HDIM=256, SDIM=128, SSZ=128.
// One WG (1024 threads = 16 waves) per item, 1 block/CU. All GEMV weights
// register-resident as f16, v_dot2_f32_f16. Stack f32 in LDS, column-parallel
// conflict-free update. buf recurrence collapsed to a 128-coeff scalar window
// over precomputed E2H (emb@We2h^T) since emb_W[PAD]==0.
// v6 = round-0 skeleton (5 barriers, raw lgkmcnt-only) with three DS-pipe cuts:
//  1. Phase B K-split 16->8: shuffles 16->6 per thread, act reads one matrix.
//  2. inst partials on wave 0 only (accih float4 + LDS-staged Wh2i), softmax
//     finishes BEFORE B2 -> no wave-0 straggle in the B2->B3 span.
//  3. softmax collapsed to pp = sigmoid(gamma*(i0-i1)), gamma = 1+softplus,
//     via v_exp/v_log/v_rcp intrinsics (identical math, eps negligible).

#define T_STEPS 127

// flat f32 output offsets (outputs, hid, stack, acts, top_elems)
#define OUT_OFF   0
#define HID_OFF   1040384
#define STACK_OFF 1048576
#define ACTS_OFF  1572864
#define TE_OFF    1580992

// ws layout (uint4 granularity for weight blobs):
//  uint4 [0,16384):      W1 = s2h (tid<512) / h2h (tid>=512), per-thread 16 uint4
//  uint4 [16384,24576):  WB = h2s (t<512) / s2u (t>=512), K-split-8, 8 uint4/thread
//  uint4 [24576,32768):  W0 = We2h^T packed [k-chunk][j] for prep_e2h
//  uint  [131072,393216): E2H f16-pairs per item: [b][r2*256+j] = (row2r2,row2r2+1)
#define WB_OFF 16384
#define E2H_OFF_U 131072

typedef _Float16 h2 __attribute__((ext_vector_type(2)));

__device__ __forceinline__ unsigned packh2(float a, float b){
  h2 v; v.x = (_Float16)a; v.y = (_Float16)b;
  return __builtin_bit_cast(unsigned, v);
}
__device__ __forceinline__ float h2loF(unsigned u){ h2 v = __builtin_bit_cast(h2,u); return (float)v.x; }
__device__ __forceinline__ float h2hiF(unsigned u){ h2 v = __builtin_bit_cast(h2,u); return (float)v.y; }

#if __has_builtin(__builtin_amdgcn_fdot2)
__device__ __forceinline__ float fdot2(unsigned a, unsigned b, float c){
  return __builtin_amdgcn_fdot2(__builtin_bit_cast(h2,a), __builtin_bit_cast(h2,b), c, false);
}
#else
__device__ __forceinline__ float fdot2(unsigned a, unsigned b, float c){
  return c + h2loF(a)*h2loF(b) + h2hiF(a)*h2hiF(b);
}
#endif

#if __has_builtin(__builtin_amdgcn_exp2f)
#define EXP2F(x) __builtin_amdgcn_exp2f(x)
#else
#define EXP2F(x) exp2f(x)
#endif
#if __has_builtin(__builtin_amdgcn_logf)
#define LOG2F(x) __builtin_amdgcn_logf(x)
#else
#define LOG2F(x) log2f(x)
#endif
#if __has_builtin(__builtin_amdgcn_rcpf)
#define RCPF(x) __builtin_amdgcn_rcpf(x)
#else
#define RCPF(x) (1.f/(x))
#endif

// raw barrier: LDS-only drain, no vmcnt (global stores don't gate the barrier)
#define BAR() asm volatile("s_waitcnt lgkmcnt(0)\n\ts_barrier" ::: "memory")

// chunked (bank-staggered) layout for packed act vectors: logical uint u ->
// physical 12*(u>>3) + (u&7).  16 chunks x 12 uints = 192 uints.
#define CHOFF(u) (12*((u)>>3) + ((u)&7))

// ---------------- prep: pack all weights to f16 blobs ----------------
__global__ void prep_pack(const float* __restrict__ We2h, const float* __restrict__ Ws2h,
                          const float* __restrict__ Wh2h, const float* __restrict__ Wh2s,
                          const float* __restrict__ Ws2u, uint4* __restrict__ out4){
  int gid = blockIdx.x*256 + threadIdx.x;    // [0, 32768)
  const float* src;
  if (gid < 16384){                          // W1: i in [0,16), t in [0,1024)
    int i = gid >> 10, t_ = gid & 1023;
    const float* S = (t_ < 512) ? Ws2h : Wh2h;
    int r = t_ & 511, jp = r >> 2, ks = r & 3;
    int j = 2*jp + (i >> 3);
    int k0 = ks*64 + (i & 7)*8;
    src = S + j*256 + k0;
  } else if (gid < 24576){                   // WB: h2s (t<512) / s2u, K-split 8
    int l = gid - 16384;
    int i = l >> 10, t_ = l & 1023;
    const float* S = (t_ < 512) ? Wh2s : Ws2u;
    int tt = t_ & 511;                       // p*8 + k, p in [0,64), k in [0,8)
    int j  = 2*(tt >> 3) + (i >> 2);         // row
    int k0 = (tt & 7)*32 + (i & 3)*8;        // dim base
    src = S + j*256 + k0;
  } else {                                   // W0: [k-chunk i8][j]
    int l = gid - 24576;
    int i8 = l >> 8, j = l & 255;
    src = We2h + j*256 + i8*8;
  }
  uint4 r4;
  r4.x = packh2(src[0], src[1]); r4.y = packh2(src[2], src[3]);
  r4.z = packh2(src[4], src[5]); r4.w = packh2(src[6], src[7]);
  out4[gid] = r4;
}

// ---------------- prep: E2H = emb @ We2h^T, f16 row-pairs ----------------
__global__ void prep_e2h(const int* __restrict__ inputs, const float* __restrict__ embW,
                         const uint4* __restrict__ w04, unsigned* __restrict__ e2hpk){
  __shared__ float emb[8][256];
  int tid = threadIdx.x;
  int r2 = blockIdx.x >> 3, bg = blockIdx.x & 7;
  for (int q=0;q<8;q++){
    int rr = q >> 2, bb = q & 3;
    int tok = inputs[(2*r2+rr)*32 + bg*4+bb];
    emb[q][tid] = embW[tok*256 + tid];
  }
  __syncthreads();
  float acc[8] = {0.f,0.f,0.f,0.f,0.f,0.f,0.f,0.f};
  for (int i8=0;i8<32;i8++){
    uint4 u = w04[i8*256 + tid];
    unsigned uu[4] = {u.x,u.y,u.z,u.w};
    #pragma unroll
    for (int c=0;c<4;c++){
      float lo = h2loF(uu[c]), hi = h2hiF(uu[c]);
      int k = i8*8 + c*2;
      #pragma unroll
      for (int q=0;q<8;q++)
        acc[q] += emb[q][k]*lo + emb[q][k+1]*hi;
    }
  }
  int base = (bg*4)*8192 + r2*256 + tid;
  #pragma unroll
  for (int bb=0;bb<4;bb++)
    e2hpk[base + bb*8192] = packh2(acc[bb], acc[4+bb]);  // (row 2r2, row 2r2+1)
}

// ---------------- main sequential kernel ----------------
__global__ __attribute__((amdgpu_flat_work_group_size(1024,1024), amdgpu_waves_per_eu(4,4)))
void srnn_main(const uint4* __restrict__ ws4, const unsigned* __restrict__ wsu,
               const float* __restrict__ b_e2h, const float* __restrict__ b_s2h,
               const float* __restrict__ b_h2h, const float* __restrict__ Wh2i,
               const float* __restrict__ b_h2i, const float* __restrict__ b_h2s,
               const float* __restrict__ b_s2u, const float* __restrict__ empty_el,
               float* __restrict__ out)
{
  __shared__ __align__(16) float    stk_s[128*128];     // stack f32, 64 KB, no pad
  __shared__ __align__(16) unsigned e2h_s[32*258];      // f16 pairs, stride 258
  __shared__ __align__(16) unsigned s_pk[192];          // tops f16, chunk-staggered
  __shared__ __align__(16) unsigned hid_pk[192];        // hid f16, chunk-staggered
  __shared__ __align__(16) float    pv_s[128], uv_s[128];
  __shared__ __align__(16) float    accih[256], acchp[256];
  __shared__ __align__(16) float    emptyf_s[128];
  __shared__ __align__(16) float    whi_s[768];         // Wh2i rows 0..2
  __shared__ float    wbuf[2][192];
  __shared__ unsigned pkwc[32];
  __shared__ float    pp_s, pq_s;

  const int tid = threadIdx.x;
  const int b   = blockIdx.x;
  const int aside = tid >> 9;           // phase A: 0=ih(s2h), 1=hp(h2h)
  const int ar  = tid & 511;
  const int ajp = ar >> 2;              // output pair 0..127
  const int aks = ar & 3;               // K-split 4 (K=64 each)
  const int pB  = tid >> 3;             // phase B output pair 0..127 (pv:0-63, uv:64-127)
  const int kB  = tid & 7;              // phase B K-split 8 (K=32 each)
  const int g   = tid >> 6;             // stack: wave id = row-group (8 rows)
  const int cp  = tid & 63;             // stack: column pair

  // ---- preload weights into registers ----
  uint4 w1r[16], wBr[8];
  #pragma unroll
  for (int i=0;i<16;i++) w1r[i] = ws4[i*1024 + tid];
  #pragma unroll
  for (int i=0;i<8;i++)  wBr[i] = ws4[WB_OFF + i*1024 + tid];

  float bA0=0.f, bA1=0.f;
  if (aks==0){
    int j0 = 2*ajp;
    if (aside==0){ bA0 = b_e2h[j0]+b_s2h[j0]; bA1 = b_e2h[j0+1]+b_s2h[j0+1]; }
    else         { bA0 = b_h2h[j0];           bA1 = b_h2h[j0+1]; }
  }
  float bB0=0.f, bB1=0.f;
  if (kB==0){
    if (pB < 64){ bB0 = b_h2s[2*pB];      bB1 = b_h2s[2*pB+1]; }
    else        { bB0 = b_s2u[2*(pB-64)]; bB1 = b_s2u[2*(pB-64)+1]; }
  }
  const float bi0=b_h2i[0], bi1=b_h2i[1], bi2=b_h2i[2];

  // ---- init LDS state ----
  const unsigned* e2hg = wsu + E2H_OFF_U + b*8192;
  #pragma unroll
  for (int q=0;q<8;q++){
    int idx = q*1024 + tid;
    e2h_s[(idx>>8)*258 + (idx&255)] = e2hg[idx];
  }
  {
    float2 e2 = *(const float2*)&empty_el[2*cp];
    #pragma unroll
    for (int j=0;j<8;j++)
      *(float2*)&stk_s[(8*g+j)*128 + 2*cp] = e2;
  }
  if (tid < 128){
    emptyf_s[tid] = empty_el[tid];
    hid_pk[CHOFF(tid)] = 0u;
    int cu = tid & 63;
    s_pk[CHOFF(tid)] = packh2(empty_el[2*cu], empty_el[2*cu+1]);
  }
  if (tid < 768) whi_s[tid] = Wh2i[tid];
  if (tid < 192){ wbuf[0][tid] = (tid==64)?1.f:0.f; wbuf[1][tid]=0.f; }
  if (tid < 32)  pkwc[tid] = (tid==0)? packh2(1.f,0.f) : 0u;
  __syncthreads();

  int cur = 0;
  for (int t=0;t<T_STEPS;++t){
    // ============ Phase A: ihid (s2h + inp-window) & hid-pre (h2h) ============
    {
      const unsigned* act  = aside ? hid_pk : s_pk;
      const unsigned* actB = act + 48*aks;
      float x0 = 0.f, x1 = 0.f;
      if (aside==0){
        #pragma unroll
        for (int q=0;q<8;q++){
          int r2 = aks*8 + q;
          unsigned cw = pkwc[r2];
          uint2 e = *(const uint2*)&e2h_s[r2*258 + 2*ajp];
          x0 = fdot2(cw, e.x, x0);
          x1 = fdot2(cw, e.y, x1);
        }
      }
      #pragma unroll
      for (int i=0;i<8;i++){
        uint4 A  = *(const uint4*)(actB + 12*(i>>1) + 4*(i&1));
        uint4 Wa = w1r[i], Wb = w1r[8+i];
        x0 = fdot2(A.x,Wa.x,x0); x0 = fdot2(A.y,Wa.y,x0);
        x0 = fdot2(A.z,Wa.z,x0); x0 = fdot2(A.w,Wa.w,x0);
        x1 = fdot2(A.x,Wb.x,x1); x1 = fdot2(A.y,Wb.y,x1);
        x1 = fdot2(A.z,Wb.z,x1); x1 = fdot2(A.w,Wb.w,x1);
      }
      x0 += __shfl_xor(x0,1); x0 += __shfl_xor(x0,2);
      x1 += __shfl_xor(x1,1); x1 += __shfl_xor(x1,2);
      if (aks==0){
        float* dst = aside ? acchp : accih;
        *(float2*)&dst[2*ajp] = make_float2(x0 + bA0, x1 + bA1);
      }
    }
    BAR();                                             // B1

    // ---- inst partials + softmax, wave 0 only ----
    if (tid < 64){
      float4 av = *(const float4*)&accih[4*tid];
      float4 q0 = *(const float4*)&whi_s[      4*tid];
      float4 q1 = *(const float4*)&whi_s[256 + 4*tid];
      float4 q2 = *(const float4*)&whi_s[512 + 4*tid];
      float p0 = av.x*q0.x + av.y*q0.y + av.z*q0.z + av.w*q0.w;
      float p1 = av.x*q1.x + av.y*q1.y + av.z*q1.z + av.w*q1.w;
      float p2 = av.x*q2.x + av.y*q2.y + av.z*q2.z + av.w*q2.w;
      #pragma unroll
      for (int o=1;o<=32;o<<=1){
        p0 += __shfl_xor(p0,o); p1 += __shfl_xor(p1,o); p2 += __shfl_xor(p2,o);
      }
      if (tid==0){
        float i0 = bi0+p0, i1 = bi1+p1, gi = bi2+p2;
        // pp = A0/(A0+A1+1e-16) with A=act^gamma, act=softmax(i0,i1)
        //    = sigmoid(gamma*(i0-i1))  (eps negligible: A0+A1 >= 2^(1-gamma)
        //      with gamma ~ 1..3 here)
        float gamma = 1.f + 0.6931471806f*LOG2F(1.f + EXP2F(1.442695041f*gi));
        float z = 1.442695041f*gamma*(i0 - i1);
        float ppv = RCPF(1.f + EXP2F(-z));
        float pqv = 1.f - ppv;
        pp_s = ppv; pq_s = pqv;
        *(float2*)&out[ACTS_OFF + t*64 + b*2] = make_float2(ppv,pqv);
      }
    }
    // ---- hid update, waves 1-2 ----
    if (tid >= 64 && tid < 192){
      int hl = tid - 64;
      float2 ih2 = *(const float2*)&accih[2*hl];
      float2 hp2 = *(const float2*)&acchp[2*hl];
      float hn0 = fmaxf(ih2.x+hp2.x, 0.f);
      float hn1 = fmaxf(ih2.y+hp2.y, 0.f);
      hid_pk[CHOFF(hl)] = packh2(hn0,hn1);
      *(float2*)&out[OUT_OFF + t*8192 + b*256 + 2*hl] = make_float2(hn0,hn1);
      if (t==T_STEPS-1) *(float2*)&out[HID_OFF + b*256 + 2*hl] = make_float2(hn0,hn1);
    }
    BAR();                                             // B2

    // ============ Phase B: h2s (new hid, pB<64) / s2u (old tops), K-split 8 ====
    {
      const unsigned* srcB = (pB < 64) ? hid_pk : s_pk;
      const uint4* cA0 = (const uint4*)(srcB + 24*kB);
      const uint4* cA1 = (const uint4*)(srcB + 24*kB + 12);
      uint4 A0 = cA0[0], A1 = cA0[1];
      uint4 A2 = cA1[0], A3 = cA1[1];
      float y0=0.f, y1=0.f;
      y0=fdot2(A0.x,wBr[0].x,y0); y0=fdot2(A0.y,wBr[0].y,y0); y0=fdot2(A0.z,wBr[0].z,y0); y0=fdot2(A0.w,wBr[0].w,y0);
      y0=fdot2(A1.x,wBr[1].x,y0); y0=fdot2(A1.y,wBr[1].y,y0); y0=fdot2(A1.z,wBr[1].z,y0); y0=fdot2(A1.w,wBr[1].w,y0);
      y0=fdot2(A2.x,wBr[2].x,y0); y0=fdot2(A2.y,wBr[2].y,y0); y0=fdot2(A2.z,wBr[2].z,y0); y0=fdot2(A2.w,wBr[2].w,y0);
      y0=fdot2(A3.x,wBr[3].x,y0); y0=fdot2(A3.y,wBr[3].y,y0); y0=fdot2(A3.z,wBr[3].z,y0); y0=fdot2(A3.w,wBr[3].w,y0);
      y1=fdot2(A0.x,wBr[4].x,y1); y1=fdot2(A0.y,wBr[4].y,y1); y1=fdot2(A0.z,wBr[4].z,y1); y1=fdot2(A0.w,wBr[4].w,y1);
      y1=fdot2(A1.x,wBr[5].x,y1); y1=fdot2(A1.y,wBr[5].y,y1); y1=fdot2(A1.z,wBr[5].z,y1); y1=fdot2(A1.w,wBr[5].w,y1);
      y1=fdot2(A2.x,wBr[6].x,y1); y1=fdot2(A2.y,wBr[6].y,y1); y1=fdot2(A2.z,wBr[6].z,y1); y1=fdot2(A2.w,wBr[6].w,y1);
      y1=fdot2(A3.x,wBr[7].x,y1); y1=fdot2(A3.y,wBr[7].y,y1); y1=fdot2(A3.z,wBr[7].z,y1); y1=fdot2(A3.w,wBr[7].w,y1);
      y0 += __shfl_xor(y0,1); y0 += __shfl_xor(y0,2); y0 += __shfl_xor(y0,4);
      y1 += __shfl_xor(y1,1); y1 += __shfl_xor(y1,2); y1 += __shfl_xor(y1,4);
      if (kB==0){
        float v0 = fmaxf(y0+bB0,0.f), v1 = fmaxf(y1+bB1,0.f);
        if (pB < 64) *(float2*)&pv_s[2*pB]      = make_float2(v0,v1);
        else         *(float2*)&uv_s[2*(pB-64)] = make_float2(v0,v1);
      }
    }
    BAR();                                             // B3
    const float pp = pp_s, pq = pq_s;

    // ============ Stack update: column-parallel, conflict-free ============
    {
      float2 w[10];                                    // rows 8g-1 .. 8g+8
      #pragma unroll
      for (int k=0;k<10;k++){
        int r = 8*g - 1 + k;
        if (r >= 0 && r <= 127)
          w[k] = *(const float2*)&stk_s[r*128 + 2*cp];
      }
      if (g == 15) w[9] = *(const float2*)&emptyf_s[2*cp];
      float2 pv2 = make_float2(0.f,0.f), uv2 = make_float2(0.f,0.f);
      if (g == 0){ pv2 = *(const float2*)&pv_s[2*cp]; uv2 = *(const float2*)&uv_s[2*cp]; }
      float2 nn[8];
      #pragma unroll
      for (int j=0;j<8;j++){
        nn[j].x = pp*w[j].x + pq*w[j+2].x;
        nn[j].y = pp*w[j].y + pq*w[j+2].y;
      }
      if (g == 0){
        nn[0].x = pp*pv2.x + pq*uv2.x;
        nn[0].y = pp*pv2.y + pq*uv2.y;
      }
      // coefficient recurrence for the collapsed buf + next-step packed pairs
      if (tid < 128){
        int k = 64+tid;
        wbuf[cur^1][k] = pp*wbuf[cur][k] + pq*wbuf[cur][k-1];
      } else if (tid < 160){
        int r2 = tid-128;
        int k1 = 65 + t - 2*r2;
        float wa = wbuf[cur][k1], wb2 = wbuf[cur][k1-1], wc2 = wbuf[cur][k1-2];
        pkwc[r2] = packh2(pp*wa+pq*wb2, pp*wb2+pq*wc2);
      }
      BAR();                                           // S_e (all reads done)
      #pragma unroll
      for (int j=0;j<8;j++)
        *(float2*)&stk_s[(8*g+j)*128 + 2*cp] = nn[j];
      if (g == 0){
        *(float2*)&out[TE_OFF + t*4096 + b*128 + 2*cp] = nn[0];
        s_pk[CHOFF(cp)]      = packh2(nn[0].x, nn[0].y);
        s_pk[CHOFF(64+cp)]   = packh2(nn[1].x, nn[1].y);
      }
    }
    BAR();                                             // S_f
    cur ^= 1;
  }

  // ---- final stack output ----
  #pragma unroll
  for (int j=0;j<8;j++){
    int r = 8*g + j;
    *(float2*)&out[STACK_OFF + b*16384 + r*128 + 2*cp] =
      *(const float2*)&stk_s[r*128 + 2*cp];
  }
}

extern "C" void kernel_launch(void* const* d_in, const int* in_sizes, int n_in,
                              void* d_out, int out_size, void* d_ws, size_t ws_size,
                              hipStream_t stream){
  const int*   inputs = (const int*)d_in[0];
  const float* embW   = (const float*)d_in[1];
  const float* We2h   = (const float*)d_in[2];
  const float* b_e2h  = (const float*)d_in[3];
  const float* Ws2h   = (const float*)d_in[4];
  const float* b_s2h  = (const float*)d_in[5];
  const float* Wh2h   = (const float*)d_in[6];
  const float* b_h2h  = (const float*)d_in[7];
  const float* Wh2i   = (const float*)d_in[8];
  const float* b_h2i  = (const float*)d_in[9];
  const float* Wh2s   = (const float*)d_in[10];
  const float* b_h2s  = (const float*)d_in[11];
  const float* Ws2u   = (const float*)d_in[12];
  const float* b_s2u  = (const float*)d_in[13];
  const float* empty  = (const float*)d_in[14];
  unsigned* wsu = (unsigned*)d_ws;

  prep_pack<<<dim3(128), dim3(256), 0, stream>>>(We2h, Ws2h, Wh2h, Wh2s, Ws2u, (uint4*)wsu);
  prep_e2h<<<dim3(256), dim3(256), 0, stream>>>(inputs, embW, ((const uint4*)wsu)+24576, wsu + E2H_OFF_U);
  srnn_main<<<dim3(32), dim3(1024), 0, stream>>>((const uint4*)wsu, (const unsigned*)wsu,
                                                 b_e2h, b_s2h, b_h2h, Wh2i, b_h2i,
                                                 b_h2s, b_s2u, empty, (float*)d_out);
}